// Round 4
// baseline (15260.471 us; speedup 1.0000x reference)
//
#include <hip/hip_runtime.h>
#include <hip/hip_bf16.h>

#define SEQ 4096
#define EMB 1024
#define HID 2048
#define G4  8192
#define NL  256

typedef __attribute__((ext_vector_type(8))) short bf16x8;
typedef __attribute__((ext_vector_type(4))) float f32x4;

static __device__ __forceinline__ unsigned short f2bf(float f) {
    unsigned int x = __builtin_bit_cast(unsigned int, f);
    return (unsigned short)((x + 0x7FFFu + ((x >> 16) & 1u)) >> 16);
}
static __device__ __forceinline__ float bf2f(unsigned short u) {
    return __builtin_bit_cast(float, ((unsigned int)u) << 16);
}
static __device__ __forceinline__ unsigned long long aload(const unsigned long long* p) {
    return __hip_atomic_load(p, __ATOMIC_RELAXED, __HIP_MEMORY_SCOPE_AGENT);
}
static __device__ __forceinline__ float fsigm(float x) {
    return 1.f / (1.f + __expf(-x));
}
static __device__ __forceinline__ float ftanh(float x) {
    return 1.f - 2.f / (__expf(2.f * x) + 1.f);
}

// ---------------- fp32 -> bf16 convert ----------------
__global__ __launch_bounds__(256) void k_f2b(const float* __restrict__ in,
                                             unsigned short* __restrict__ out, int n) {
    int i = (blockIdx.x * 256 + threadIdx.x) * 4;
    if (i < n) {
        float4 v = *(const float4*)&in[i];
        ushort4 u;
        u.x = f2bf(v.x); u.y = f2bf(v.y); u.z = f2bf(v.z); u.w = f2bf(v.w);
        *(ushort4*)&out[i] = u;
    }
}

// ---------------- embedding gather + cast ----------------
__global__ __launch_bounds__(256) void k_emb(const int* __restrict__ ids,
                                             const float* __restrict__ W_emb,
                                             unsigned short* __restrict__ out) {
    int t = blockIdx.x;
    int e0 = threadIdx.x * 4;
    const float4 v = *(const float4*)&W_emb[(size_t)ids[t] * EMB + e0];
    ushort4 u;
    u.x = f2bf(v.x); u.y = f2bf(v.y); u.z = f2bf(v.z); u.w = f2bf(v.w);
    *(ushort4*)&out[(size_t)t * EMB + e0] = u;
}

// ---------------- bf16 MFMA GEMM:  C[M,N] = A[M,K] * B[N,K]^T + bias ----------------
#define BM 128
#define BN 128
#define BK 32
__global__ __launch_bounds__(256) void k_gemm_bt(
    const unsigned short* __restrict__ A, const unsigned short* __restrict__ B,
    const float* __restrict__ bias1, const float* __restrict__ bias2,
    float* __restrict__ Cf, unsigned short* __restrict__ Cb,
    int M, int N, int K)
{
    __shared__ unsigned short As[BM * BK];
    __shared__ unsigned short Bs[BN * BK];
    const int bm = blockIdx.x * BM;
    const int bn = blockIdx.y * BN;
    const int tid = threadIdx.x;
    const int wave = tid >> 6, lane = tid & 63;
    const int wm = (wave & 1) * 64, wn = (wave >> 1) * 64;
    const int row16 = lane & 15, quad = lane >> 4;

    f32x4 acc[4][4];
#pragma unroll
    for (int i = 0; i < 4; ++i)
#pragma unroll
        for (int j = 0; j < 4; ++j) acc[i][j] = (f32x4){0.f, 0.f, 0.f, 0.f};

    for (int k0 = 0; k0 < K; k0 += BK) {
        __syncthreads();
#pragma unroll
        for (int s = 0; s < 2; ++s) {
            int c = tid + s * 256;
            int r = c >> 2, col = (c & 3) * 8;
            *(uint4*)&As[r * BK + col] = *(const uint4*)&A[(size_t)(bm + r) * K + k0 + col];
            *(uint4*)&Bs[r * BK + col] = *(const uint4*)&B[(size_t)(bn + r) * K + k0 + col];
        }
        __syncthreads();
        bf16x8 af[4], bfr[4];
#pragma unroll
        for (int i = 0; i < 4; ++i) {
            af[i]  = *(const bf16x8*)&As[(wm + i * 16 + row16) * BK + quad * 8];
            bfr[i] = *(const bf16x8*)&Bs[(wn + i * 16 + row16) * BK + quad * 8];
        }
#pragma unroll
        for (int i = 0; i < 4; ++i)
#pragma unroll
            for (int j = 0; j < 4; ++j)
                acc[i][j] = __builtin_amdgcn_mfma_f32_16x16x32_bf16(af[i], bfr[j], acc[i][j], 0, 0, 0);
    }

#pragma unroll
    for (int j = 0; j < 4; ++j) {
        int col = bn + wn + j * 16 + row16;
        float bsum = (bias1 ? bias1[col] : 0.f) + (bias2 ? bias2[col] : 0.f);
#pragma unroll
        for (int i = 0; i < 4; ++i) {
#pragma unroll
            for (int r = 0; r < 4; ++r) {
                int row = bm + wm + i * 16 + quad * 4 + r;
                float v = acc[i][j][r] + bsum;
                if (Cf) Cf[(size_t)row * N + col] = v;
                else    Cb[(size_t)row * N + col] = f2bf(v);
            }
        }
    }
}

// ---------------- persistent LSTM recurrence (register-direct MFMA) ----------------
// 256 blocks x 1024 threads, 1 block/CU (88KB LDS dummy forces it). Block b owns
// h[b*8..b*8+8) and gate rows {q*2048 + b*8 + j}. Wave w owns k-cols
// [w*128, w*128+128): 8 A-frags (both row groups) in 32 VGPRs, polls its own 16
// tagged 8B words straight into the MFMA B-operand (no LDS staging, no fences).
// Per step: poll(16 words, re-poll all per round) -> 8 MFMAs -> barrier ->
// partials to LDS -> barrier -> wave0: reduce + fast activation + publish.
#define LSTM_LDS 90112
__global__ __launch_bounds__(1024, 1) void k_lstm(
    const unsigned short* __restrict__ Whhb, // [8192,2048] bf16
    const unsigned short* __restrict__ xg,   // [4096,8192] bf16
    const float* __restrict__ h0, const float* __restrict__ c0,
    unsigned short* __restrict__ hsb,        // [4096,2048] bf16
    float* __restrict__ outHC,               // d_out + SEQ*NL : [hL(2048), cL(2048)]
    unsigned long long* __restrict__ hcomm)  // [2][1024] tagged h word-pairs
{
    extern __shared__ char smem[];
    float* LDSp = (float*)smem;              // [32 rows][stride 20] partials (2.5KB)

    const int b = blockIdx.x, tid = threadIdx.x;
    const int wave = tid >> 6, lane = tid & 63;
    const int sub = lane & 15, quad = lane >> 4;

    // A-fragments: rows m=sub of row-group rg (rg0: gates q=0,1 ; rg1: q=2,3),
    // k-cols wave*128 + c*32 + quad*8.
    const int qa = (sub >> 3), qb = 2 + (sub >> 3), j = sub & 7;
    const unsigned short* wa = Whhb + ((size_t)(qa * HID + b * 8 + j)) * HID + wave * 128 + quad * 8;
    const unsigned short* wb = Whhb + ((size_t)(qb * HID + b * 8 + j)) * HID + wave * 128 + quad * 8;
    bf16x8 afrA[4], afrB[4];
#pragma unroll
    for (int c = 0; c < 4; ++c) {
        afrA[c] = *(const bf16x8*)(wa + c * 32);
        afrB[c] = *(const bf16x8*)(wb + c * 32);
    }

    float creg = 0.f;
    if (tid < 8) creg = c0[b * 8 + tid];

    for (int t = 0; t < SEQ; ++t) {
        // wave0 activation lanes prefetch their 4 x-gate values
        float xq0 = 0.f, xq1 = 0.f, xq2 = 0.f, xq3 = 0.f;
        if (wave == 0 && lane < 8) {
            const unsigned short* xr = xg + (size_t)t * G4 + b * 8 + lane;
            xq0 = bf2f(xr[0]);
            xq1 = bf2f(xr[2048]);
            xq2 = bf2f(xr[4096]);
            xq3 = bf2f(xr[6144]);
        }

        f32x4 acc0 = (f32x4){0.f, 0.f, 0.f, 0.f};
        f32x4 acc1 = (f32x4){0.f, 0.f, 0.f, 0.f};

        if (t == 0) {
#pragma unroll
            for (int c = 0; c < 4; ++c) {
                const float* hp = h0 + wave * 128 + c * 32 + quad * 8;
                float4 va = *(const float4*)hp;
                float4 vb = *(const float4*)(hp + 4);
                uint4 d;
                d.x = (unsigned)f2bf(va.x) | ((unsigned)f2bf(va.y) << 16);
                d.y = (unsigned)f2bf(va.z) | ((unsigned)f2bf(va.w) << 16);
                d.z = (unsigned)f2bf(vb.x) | ((unsigned)f2bf(vb.y) << 16);
                d.w = (unsigned)f2bf(vb.z) | ((unsigned)f2bf(vb.w) << 16);
                bf16x8 hf = __builtin_bit_cast(bf16x8, d);
                acc0 = __builtin_amdgcn_mfma_f32_16x16x32_bf16(afrA[c], hf, acc0, 0, 0, 0);
                acc1 = __builtin_amdgcn_mfma_f32_16x16x32_bf16(afrB[c], hf, acc1, 0, 0, 0);
            }
        } else {
            // poll this wave's 16 words; re-issue ALL each round (1-RTT detection)
            const unsigned long long* base =
                hcomm + (size_t)((t - 1) & 1) * 1024 + wave * 64 + quad * 4;
            const unsigned tag = (unsigned)t;
            unsigned long long w[16];
            for (;;) {
#pragma unroll
                for (int c = 0; c < 4; ++c)
#pragma unroll
                    for (int i = 0; i < 4; ++i)
                        w[c * 4 + i] = aload(base + c * 16 + i);
                bool ok = true;
#pragma unroll
                for (int k = 0; k < 16; ++k) ok &= ((unsigned)(w[k] >> 32) == tag);
                if (ok) break;
            }
#pragma unroll
            for (int c = 0; c < 4; ++c) {
                uint4 d;
                d.x = (unsigned)w[c * 4 + 0];
                d.y = (unsigned)w[c * 4 + 1];
                d.z = (unsigned)w[c * 4 + 2];
                d.w = (unsigned)w[c * 4 + 3];
                bf16x8 hf = __builtin_bit_cast(bf16x8, d);
                acc0 = __builtin_amdgcn_mfma_f32_16x16x32_bf16(afrA[c], hf, acc0, 0, 0, 0);
                acc1 = __builtin_amdgcn_mfma_f32_16x16x32_bf16(afrB[c], hf, acc1, 0, 0, 0);
            }
        }

        __syncthreads();   // W: previous step's wave0 LDSp reads are done
        if (sub == 0) {
#pragma unroll
            for (int r = 0; r < 4; ++r) {
                LDSp[(quad * 4 + r) * 20 + wave]        = acc0[r];
                LDSp[(16 + quad * 4 + r) * 20 + wave]   = acc1[r];
            }
        }
        __syncthreads();   // R: partials visible

        if (wave == 0) {
            float g = 0.f;
            if (lane < 32) {
                const float* rp = LDSp + lane * 20;
                f32x4 s = *(const f32x4*)rp;
                s += *(const f32x4*)(rp + 4);
                s += *(const f32x4*)(rp + 8);
                s += *(const f32x4*)(rp + 12);
                g = s[0] + s[1] + s[2] + s[3];
            }
            // lane L (<32) holds gate row q=L>>3, j=L&7
            float gF = __shfl(g, 8 + lane);
            float gG = __shfl(g, 16 + lane);
            float gO = __shfl(g, 24 + lane);
            if (lane < 8) {
                float gi = g  + xq0;
                float gf = gF + xq1;
                float gg = gG + xq2;
                float go = gO + xq3;
                float i_ = fsigm(gi);
                float f_ = fsigm(gf);
                float g_ = ftanh(gg);
                float o_ = fsigm(go);
                float cn = f_ * creg + i_ * g_;
                float hn = o_ * ftanh(cn);
                creg = cn;
                unsigned hv = (unsigned)f2bf(hn);
                unsigned pv = (unsigned)__shfl((int)hv, lane ^ 1);
                if (!(lane & 1)) {
                    unsigned long long wrd =
                        (((unsigned long long)(unsigned)(t + 1)) << 32)
                        | (unsigned long long)((pv << 16) | hv);
                    __hip_atomic_store(&hcomm[(size_t)(t & 1) * 1024 + b * 4 + (lane >> 1)],
                                       wrd, __ATOMIC_RELAXED, __HIP_MEMORY_SCOPE_AGENT);
                }
                hsb[(size_t)t * HID + b * 8 + lane] = (unsigned short)hv;
                if (t == SEQ - 1) {
                    outHC[b * 8 + lane] = hn;
                    outHC[HID + b * 8 + lane] = cn;
                }
            }
        }
        // next iteration's barrier W protects LDSp against overwrite;
        // the tag chain protects hcomm slot reuse.
    }
}

// ---------------- relu + log_softmax over rows of 256 ----------------
__global__ __launch_bounds__(256) void k_softmax(const float* __restrict__ logits,
                                                 float* __restrict__ out) {
    int row = blockIdx.x * 4 + (threadIdx.x >> 6);
    int lane = threadIdx.x & 63;
    const float* Lr = logits + (size_t)row * NL;
    float4 v = *(const float4*)&Lr[lane * 4];
    v.x = fmaxf(v.x, 0.f); v.y = fmaxf(v.y, 0.f);
    v.z = fmaxf(v.z, 0.f); v.w = fmaxf(v.w, 0.f);
    float m = fmaxf(fmaxf(v.x, v.y), fmaxf(v.z, v.w));
#pragma unroll
    for (int off = 32; off > 0; off >>= 1) m = fmaxf(m, __shfl_xor(m, off));
    float e = __expf(v.x - m) + __expf(v.y - m) + __expf(v.z - m) + __expf(v.w - m);
#pragma unroll
    for (int off = 32; off > 0; off >>= 1) e += __shfl_xor(e, off);
    float ls = __logf(e) + m;
    float4 o;
    o.x = v.x - ls; o.y = v.y - ls; o.z = v.z - ls; o.w = v.w - ls;
    *(float4*)&out[(size_t)row * NL + lane * 4] = o;
}

extern "C" void kernel_launch(void* const* d_in, const int* in_sizes, int n_in,
                              void* d_out, int out_size, void* d_ws, size_t ws_size,
                              hipStream_t stream) {
    const int*   ids   = (const int*)d_in[0];
    const float* h0    = (const float*)d_in[1];
    const float* c0    = (const float*)d_in[2];
    const float* W_emb = (const float*)d_in[3];
    const float* W_ih  = (const float*)d_in[4];
    const float* W_hh  = (const float*)d_in[5];
    const float* b_ih  = (const float*)d_in[6];
    const float* b_hh  = (const float*)d_in[7];
    const float* W_out = (const float*)d_in[8];
    const float* b_out = (const float*)d_in[9];
    float* out = (float*)d_out;

    char* ws = (char*)d_ws;
    unsigned short* xg    = (unsigned short*)(ws);                 // 64MB  [4096,8192] bf16
    unsigned short* hsb   = (unsigned short*)(ws + 67108864);      // 16MB  [4096,2048] bf16
    unsigned short* Wihb  = (unsigned short*)(ws + 83886080);      // 16MB
    unsigned short* embb  = (unsigned short*)(ws + 100663296);     // 8MB
    unsigned short* Woutb = (unsigned short*)(ws + 109051904);     // 1MB
    float*          logit = (float*)(ws + 110100480);              // 4MB
    unsigned short* Whhb  = (unsigned short*)(ws + 114294784);     // 32MB [8192,2048] bf16
    unsigned long long* hcomm = (unsigned long long*)(ws + 147849216); // 16KB (0xAA poison != any tag)

    k_f2b<<<(G4 * EMB / 4 + 255) / 256, 256, 0, stream>>>(W_ih, Wihb, G4 * EMB);
    k_f2b<<<(NL * HID / 4 + 255) / 256, 256, 0, stream>>>(W_out, Woutb, NL * HID);
    k_f2b<<<(G4 * HID / 4 + 255) / 256, 256, 0, stream>>>(W_hh, Whhb, G4 * HID);
    k_emb<<<SEQ, 256, 0, stream>>>(ids, W_emb, embb);

    dim3 g1(SEQ / BM, G4 / BN);
    k_gemm_bt<<<g1, 256, 0, stream>>>(embb, Wihb, b_ih, b_hh, nullptr, xg, SEQ, G4, EMB);

    hipFuncSetAttribute((const void*)k_lstm, hipFuncAttributeMaxDynamicSharedMemorySize, LSTM_LDS);
    k_lstm<<<256, 1024, LSTM_LDS, stream>>>(Whhb, xg, h0, c0, hsb, out + (size_t)SEQ * NL, hcomm);

    dim3 g2(SEQ / BM, NL / BN);
    k_gemm_bt<<<g2, 256, 0, stream>>>(hsb, Woutb, b_out, nullptr, logit, nullptr, SEQ, NL, HID);

    k_softmax<<<SEQ / 4, 256, 0, stream>>>(logit, out);
}

// Round 5
// 11347.151 us; speedup vs baseline: 1.3449x; 1.3449x over previous
//
#include <hip/hip_runtime.h>
#include <hip/hip_bf16.h>

#define SEQ 4096
#define EMB 1024
#define HID 2048
#define G4  8192
#define NL  256

typedef __attribute__((ext_vector_type(8))) short bf16x8;
typedef __attribute__((ext_vector_type(4))) float f32x4;

static __device__ __forceinline__ unsigned short f2bf(float f) {
    unsigned int x = __builtin_bit_cast(unsigned int, f);
    return (unsigned short)((x + 0x7FFFu + ((x >> 16) & 1u)) >> 16);
}
static __device__ __forceinline__ float bf2f(unsigned short u) {
    return __builtin_bit_cast(float, ((unsigned int)u) << 16);
}
static __device__ __forceinline__ unsigned long long aload(const unsigned long long* p) {
    return __hip_atomic_load(p, __ATOMIC_RELAXED, __HIP_MEMORY_SCOPE_AGENT);
}
static __device__ __forceinline__ float fsigm(float x) {
    return 1.f / (1.f + __expf(-x));
}
static __device__ __forceinline__ float ftanh(float x) {
    return 1.f - 2.f / (__expf(2.f * x) + 1.f);
}

// ---------------- fp32 -> bf16 convert ----------------
__global__ __launch_bounds__(256) void k_f2b(const float* __restrict__ in,
                                             unsigned short* __restrict__ out, int n) {
    int i = (blockIdx.x * 256 + threadIdx.x) * 4;
    if (i < n) {
        float4 v = *(const float4*)&in[i];
        ushort4 u;
        u.x = f2bf(v.x); u.y = f2bf(v.y); u.z = f2bf(v.z); u.w = f2bf(v.w);
        *(ushort4*)&out[i] = u;
    }
}

// ---------------- embedding gather + cast ----------------
__global__ __launch_bounds__(256) void k_emb(const int* __restrict__ ids,
                                             const float* __restrict__ W_emb,
                                             unsigned short* __restrict__ out) {
    int t = blockIdx.x;
    int e0 = threadIdx.x * 4;
    const float4 v = *(const float4*)&W_emb[(size_t)ids[t] * EMB + e0];
    ushort4 u;
    u.x = f2bf(v.x); u.y = f2bf(v.y); u.z = f2bf(v.z); u.w = f2bf(v.w);
    *(ushort4*)&out[(size_t)t * EMB + e0] = u;
}

// ---------------- bf16 MFMA GEMM:  C[M,N] = A[M,K] * B[N,K]^T + bias ----------------
#define BM 128
#define BN 128
#define BK 32
__global__ __launch_bounds__(256) void k_gemm_bt(
    const unsigned short* __restrict__ A, const unsigned short* __restrict__ B,
    const float* __restrict__ bias1, const float* __restrict__ bias2,
    float* __restrict__ Cf, unsigned short* __restrict__ Cb,
    int M, int N, int K)
{
    __shared__ unsigned short As[BM * BK];
    __shared__ unsigned short Bs[BN * BK];
    const int bm = blockIdx.x * BM;
    const int bn = blockIdx.y * BN;
    const int tid = threadIdx.x;
    const int wave = tid >> 6, lane = tid & 63;
    const int wm = (wave & 1) * 64, wn = (wave >> 1) * 64;
    const int row16 = lane & 15, quad = lane >> 4;

    f32x4 acc[4][4];
#pragma unroll
    for (int i = 0; i < 4; ++i)
#pragma unroll
        for (int j = 0; j < 4; ++j) acc[i][j] = (f32x4){0.f, 0.f, 0.f, 0.f};

    for (int k0 = 0; k0 < K; k0 += BK) {
        __syncthreads();
#pragma unroll
        for (int s = 0; s < 2; ++s) {
            int c = tid + s * 256;
            int r = c >> 2, col = (c & 3) * 8;
            *(uint4*)&As[r * BK + col] = *(const uint4*)&A[(size_t)(bm + r) * K + k0 + col];
            *(uint4*)&Bs[r * BK + col] = *(const uint4*)&B[(size_t)(bn + r) * K + k0 + col];
        }
        __syncthreads();
        bf16x8 af[4], bfr[4];
#pragma unroll
        for (int i = 0; i < 4; ++i) {
            af[i]  = *(const bf16x8*)&As[(wm + i * 16 + row16) * BK + quad * 8];
            bfr[i] = *(const bf16x8*)&Bs[(wn + i * 16 + row16) * BK + quad * 8];
        }
#pragma unroll
        for (int i = 0; i < 4; ++i)
#pragma unroll
            for (int j = 0; j < 4; ++j)
                acc[i][j] = __builtin_amdgcn_mfma_f32_16x16x32_bf16(af[i], bfr[j], acc[i][j], 0, 0, 0);
    }

#pragma unroll
    for (int j = 0; j < 4; ++j) {
        int col = bn + wn + j * 16 + row16;
        float bsum = (bias1 ? bias1[col] : 0.f) + (bias2 ? bias2[col] : 0.f);
#pragma unroll
        for (int i = 0; i < 4; ++i) {
#pragma unroll
            for (int r = 0; r < 4; ++r) {
                int row = bm + wm + i * 16 + quad * 4 + r;
                float v = acc[i][j][r] + bsum;
                if (Cf) Cf[(size_t)row * N + col] = v;
                else    Cb[(size_t)row * N + col] = f2bf(v);
            }
        }
    }
}

// ---------------- persistent LSTM recurrence (register-direct MFMA) ----------------
// 256 blocks x 1024 threads, 1 block/CU (88KB LDS dummy forces it). Block b owns
// h[b*8..b*8+8) and gate rows {q*2048 + b*8 + j}. Wave w owns k-cols
// [w*128, w*128+128): 8 A-frags (both row groups) in 32 VGPRs. Poll: lane L polls
// ONE tagged 8B word (w*64+L) with s_sleep backoff (16x less LLC pressure than
// r4's 16-word re-poll, which line-serialized the LLC); 16 shfls route the data
// into B-fragment lanes. One barrier/step (LDSp double-buffered), wave0 epilogue.
#define LSTM_LDS 90112
__global__ __launch_bounds__(1024, 1) void k_lstm(
    const unsigned short* __restrict__ Whhb, // [8192,2048] bf16
    const unsigned short* __restrict__ xg,   // [4096,8192] bf16
    const float* __restrict__ h0, const float* __restrict__ c0,
    unsigned short* __restrict__ hsb,        // [4096,2048] bf16
    float* __restrict__ outHC,               // d_out + SEQ*NL : [hL(2048), cL(2048)]
    unsigned long long* __restrict__ hcomm)  // [2][1024] tagged h word-pairs
{
    extern __shared__ char smem[];
    float* LDSp = (float*)smem;              // 2 buffers x [32 rows][stride 20]

    const int b = blockIdx.x, tid = threadIdx.x;
    const int wave = tid >> 6, lane = tid & 63;
    const int sub = lane & 15, quad = lane >> 4;

    // A-fragments: rows m=sub of row-group rg (rg0: gates q=0,1 ; rg1: q=2,3),
    // k-cols wave*128 + c*32 + quad*8.
    const int qa = (sub >> 3), qb = 2 + (sub >> 3), j = sub & 7;
    const unsigned short* wa = Whhb + ((size_t)(qa * HID + b * 8 + j)) * HID + wave * 128 + quad * 8;
    const unsigned short* wb = Whhb + ((size_t)(qb * HID + b * 8 + j)) * HID + wave * 128 + quad * 8;
    bf16x8 afrA[4], afrB[4];
#pragma unroll
    for (int c = 0; c < 4; ++c) {
        afrA[c] = *(const bf16x8*)(wa + c * 32);
        afrB[c] = *(const bf16x8*)(wb + c * 32);
    }

    float creg = 0.f;
    if (tid < 8) creg = c0[b * 8 + tid];

    for (int t = 0; t < SEQ; ++t) {
        // wave0 activation lanes prefetch their 4 x-gate values
        float xq0 = 0.f, xq1 = 0.f, xq2 = 0.f, xq3 = 0.f;
        if (wave == 0 && lane < 8) {
            const unsigned short* xr = xg + (size_t)t * G4 + b * 8 + lane;
            xq0 = bf2f(xr[0]);
            xq1 = bf2f(xr[2048]);
            xq2 = bf2f(xr[4096]);
            xq3 = bf2f(xr[6144]);
        }

        f32x4 acc0 = (f32x4){0.f, 0.f, 0.f, 0.f};
        f32x4 acc1 = (f32x4){0.f, 0.f, 0.f, 0.f};

        if (t == 0) {
#pragma unroll
            for (int c = 0; c < 4; ++c) {
                const float* hp = h0 + wave * 128 + c * 32 + quad * 8;
                float4 va = *(const float4*)hp;
                float4 vb = *(const float4*)(hp + 4);
                uint4 d;
                d.x = (unsigned)f2bf(va.x) | ((unsigned)f2bf(va.y) << 16);
                d.y = (unsigned)f2bf(va.z) | ((unsigned)f2bf(va.w) << 16);
                d.z = (unsigned)f2bf(vb.x) | ((unsigned)f2bf(vb.y) << 16);
                d.w = (unsigned)f2bf(vb.z) | ((unsigned)f2bf(vb.w) << 16);
                bf16x8 hf = __builtin_bit_cast(bf16x8, d);
                acc0 = __builtin_amdgcn_mfma_f32_16x16x32_bf16(afrA[c], hf, acc0, 0, 0, 0);
                acc1 = __builtin_amdgcn_mfma_f32_16x16x32_bf16(afrB[c], hf, acc1, 0, 0, 0);
            }
        } else {
            // lane L polls its own word; divergent exit = all-64 detection in 1 RTT
            const unsigned long long* src = hcomm + (size_t)((t - 1) & 1) * 1024 + wave * 64;
            const unsigned tag = (unsigned)t;
            unsigned long long x;
            for (;;) {
                x = aload(&src[lane]);
                if ((unsigned)(x >> 32) == tag) break;
                __builtin_amdgcn_s_sleep(1);
            }
            int myd = (int)(unsigned)x;
#pragma unroll
            for (int c = 0; c < 4; ++c) {
                const int sl = c * 16 + quad * 4;
                uint4 d;
                d.x = (unsigned)__shfl(myd, sl + 0);
                d.y = (unsigned)__shfl(myd, sl + 1);
                d.z = (unsigned)__shfl(myd, sl + 2);
                d.w = (unsigned)__shfl(myd, sl + 3);
                bf16x8 hf = __builtin_bit_cast(bf16x8, d);
                acc0 = __builtin_amdgcn_mfma_f32_16x16x32_bf16(afrA[c], hf, acc0, 0, 0, 0);
                acc1 = __builtin_amdgcn_mfma_f32_16x16x32_bf16(afrB[c], hf, acc1, 0, 0, 0);
            }
        }

        // partials -> double-buffered LDS, ONE barrier per step.
        // Buffer t&1: wave0 reads it after this barrier; other waves next write
        // it at step t+2, ordered by barrier(t+1) which wave0 only reaches after
        // finishing these reads.
        float* P = LDSp + (t & 1) * 640;
        if (sub == 0) {
#pragma unroll
            for (int r = 0; r < 4; ++r) {
                P[(quad * 4 + r) * 20 + wave]      = acc0[r];
                P[(16 + quad * 4 + r) * 20 + wave] = acc1[r];
            }
        }
        __syncthreads();

        if (wave == 0) {
            float g = 0.f;
            if (lane < 32) {
                const float* rp = P + lane * 20;
                f32x4 s = *(const f32x4*)rp;
                s += *(const f32x4*)(rp + 4);
                s += *(const f32x4*)(rp + 8);
                s += *(const f32x4*)(rp + 12);
                g = s[0] + s[1] + s[2] + s[3];
            }
            // lane L (<32) holds gate row q=L>>3, j=L&7
            float gF = __shfl(g, 8 + lane);
            float gG = __shfl(g, 16 + lane);
            float gO = __shfl(g, 24 + lane);
            if (lane < 8) {
                float gi = g  + xq0;
                float gf = gF + xq1;
                float gg = gG + xq2;
                float go = gO + xq3;
                float i_ = fsigm(gi);
                float f_ = fsigm(gf);
                float g_ = ftanh(gg);
                float o_ = fsigm(go);
                float cn = f_ * creg + i_ * g_;
                float hn = o_ * ftanh(cn);
                creg = cn;
                unsigned hv = (unsigned)f2bf(hn);
                unsigned pv = (unsigned)__shfl((int)hv, lane ^ 1);
                if (!(lane & 1)) {
                    unsigned long long wrd =
                        (((unsigned long long)(unsigned)(t + 1)) << 32)
                        | (unsigned long long)((pv << 16) | hv);
                    __hip_atomic_store(&hcomm[(size_t)(t & 1) * 1024 + b * 4 + (lane >> 1)],
                                       wrd, __ATOMIC_RELAXED, __HIP_MEMORY_SCOPE_AGENT);
                }
                hsb[(size_t)t * HID + b * 8 + lane] = (unsigned short)hv;
                if (t == SEQ - 1) {
                    outHC[b * 8 + lane] = hn;
                    outHC[HID + b * 8 + lane] = cn;
                }
            }
        }
    }
}

// ---------------- relu + log_softmax over rows of 256 ----------------
__global__ __launch_bounds__(256) void k_softmax(const float* __restrict__ logits,
                                                 float* __restrict__ out) {
    int row = blockIdx.x * 4 + (threadIdx.x >> 6);
    int lane = threadIdx.x & 63;
    const float* Lr = logits + (size_t)row * NL;
    float4 v = *(const float4*)&Lr[lane * 4];
    v.x = fmaxf(v.x, 0.f); v.y = fmaxf(v.y, 0.f);
    v.z = fmaxf(v.z, 0.f); v.w = fmaxf(v.w, 0.f);
    float m = fmaxf(fmaxf(v.x, v.y), fmaxf(v.z, v.w));
#pragma unroll
    for (int off = 32; off > 0; off >>= 1) m = fmaxf(m, __shfl_xor(m, off));
    float e = __expf(v.x - m) + __expf(v.y - m) + __expf(v.z - m) + __expf(v.w - m);
#pragma unroll
    for (int off = 32; off > 0; off >>= 1) e += __shfl_xor(e, off);
    float ls = __logf(e) + m;
    float4 o;
    o.x = v.x - ls; o.y = v.y - ls; o.z = v.z - ls; o.w = v.w - ls;
    *(float4*)&out[(size_t)row * NL + lane * 4] = o;
}

extern "C" void kernel_launch(void* const* d_in, const int* in_sizes, int n_in,
                              void* d_out, int out_size, void* d_ws, size_t ws_size,
                              hipStream_t stream) {
    const int*   ids   = (const int*)d_in[0];
    const float* h0    = (const float*)d_in[1];
    const float* c0    = (const float*)d_in[2];
    const float* W_emb = (const float*)d_in[3];
    const float* W_ih  = (const float*)d_in[4];
    const float* W_hh  = (const float*)d_in[5];
    const float* b_ih  = (const float*)d_in[6];
    const float* b_hh  = (const float*)d_in[7];
    const float* W_out = (const float*)d_in[8];
    const float* b_out = (const float*)d_in[9];
    float* out = (float*)d_out;

    char* ws = (char*)d_ws;
    unsigned short* xg    = (unsigned short*)(ws);                 // 64MB  [4096,8192] bf16
    unsigned short* hsb   = (unsigned short*)(ws + 67108864);      // 16MB  [4096,2048] bf16
    unsigned short* Wihb  = (unsigned short*)(ws + 83886080);      // 16MB
    unsigned short* embb  = (unsigned short*)(ws + 100663296);     // 8MB
    unsigned short* Woutb = (unsigned short*)(ws + 109051904);     // 1MB
    float*          logit = (float*)(ws + 110100480);              // 4MB
    unsigned short* Whhb  = (unsigned short*)(ws + 114294784);     // 32MB [8192,2048] bf16
    unsigned long long* hcomm = (unsigned long long*)(ws + 147849216); // 16KB (0xAA poison != any tag)

    k_f2b<<<(G4 * EMB / 4 + 255) / 256, 256, 0, stream>>>(W_ih, Wihb, G4 * EMB);
    k_f2b<<<(NL * HID / 4 + 255) / 256, 256, 0, stream>>>(W_out, Woutb, NL * HID);
    k_f2b<<<(G4 * HID / 4 + 255) / 256, 256, 0, stream>>>(W_hh, Whhb, G4 * HID);
    k_emb<<<SEQ, 256, 0, stream>>>(ids, W_emb, embb);

    dim3 g1(SEQ / BM, G4 / BN);
    k_gemm_bt<<<g1, 256, 0, stream>>>(embb, Wihb, b_ih, b_hh, nullptr, xg, SEQ, G4, EMB);

    hipFuncSetAttribute((const void*)k_lstm, hipFuncAttributeMaxDynamicSharedMemorySize, LSTM_LDS);
    k_lstm<<<256, 1024, LSTM_LDS, stream>>>(Whhb, xg, h0, c0, hsb, out + (size_t)SEQ * NL, hcomm);

    dim3 g2(SEQ / BM, NL / BN);
    k_gemm_bt<<<g2, 256, 0, stream>>>(hsb, Woutb, b_out, nullptr, logit, nullptr, SEQ, NL, HID);

    k_softmax<<<SEQ / 4, 256, 0, stream>>>(logit, out);
}

// Round 6
// 10687.258 us; speedup vs baseline: 1.4279x; 1.0617x over previous
//
#include <hip/hip_runtime.h>
#include <hip/hip_bf16.h>

#define SEQ 4096
#define EMB 1024
#define HID 2048
#define G4  8192
#define NL  256

typedef __attribute__((ext_vector_type(8))) short bf16x8;
typedef __attribute__((ext_vector_type(4))) float f32x4;

static __device__ __forceinline__ unsigned short f2bf(float f) {
    unsigned int x = __builtin_bit_cast(unsigned int, f);
    return (unsigned short)((x + 0x7FFFu + ((x >> 16) & 1u)) >> 16);
}
static __device__ __forceinline__ float bf2f(unsigned short u) {
    return __builtin_bit_cast(float, ((unsigned int)u) << 16);
}
static __device__ __forceinline__ unsigned long long aload(const unsigned long long* p) {
    return __hip_atomic_load(p, __ATOMIC_RELAXED, __HIP_MEMORY_SCOPE_AGENT);
}
static __device__ __forceinline__ float fsigm(float x) {
    return 1.f / (1.f + __expf(-x));
}
static __device__ __forceinline__ float ftanh(float x) {
    return 1.f - 2.f / (__expf(2.f * x) + 1.f);
}

// ---------------- fp32 -> bf16 convert ----------------
__global__ __launch_bounds__(256) void k_f2b(const float* __restrict__ in,
                                             unsigned short* __restrict__ out, int n) {
    int i = (blockIdx.x * 256 + threadIdx.x) * 4;
    if (i < n) {
        float4 v = *(const float4*)&in[i];
        ushort4 u;
        u.x = f2bf(v.x); u.y = f2bf(v.y); u.z = f2bf(v.z); u.w = f2bf(v.w);
        *(ushort4*)&out[i] = u;
    }
}

// ---------------- embedding gather + cast ----------------
__global__ __launch_bounds__(256) void k_emb(const int* __restrict__ ids,
                                             const float* __restrict__ W_emb,
                                             unsigned short* __restrict__ out) {
    int t = blockIdx.x;
    int e0 = threadIdx.x * 4;
    const float4 v = *(const float4*)&W_emb[(size_t)ids[t] * EMB + e0];
    ushort4 u;
    u.x = f2bf(v.x); u.y = f2bf(v.y); u.z = f2bf(v.z); u.w = f2bf(v.w);
    *(ushort4*)&out[(size_t)t * EMB + e0] = u;
}

// ---------------- bf16 MFMA GEMM:  C[M,N] = A[M,K] * B[N,K]^T + bias ----------------
#define BM 128
#define BN 128
#define BK 32
__global__ __launch_bounds__(256) void k_gemm_bt(
    const unsigned short* __restrict__ A, const unsigned short* __restrict__ B,
    const float* __restrict__ bias1, const float* __restrict__ bias2,
    float* __restrict__ Cf, unsigned short* __restrict__ Cb,
    int M, int N, int K)
{
    __shared__ unsigned short As[BM * BK];
    __shared__ unsigned short Bs[BN * BK];
    const int bm = blockIdx.x * BM;
    const int bn = blockIdx.y * BN;
    const int tid = threadIdx.x;
    const int wave = tid >> 6, lane = tid & 63;
    const int wm = (wave & 1) * 64, wn = (wave >> 1) * 64;
    const int row16 = lane & 15, quad = lane >> 4;

    f32x4 acc[4][4];
#pragma unroll
    for (int i = 0; i < 4; ++i)
#pragma unroll
        for (int j = 0; j < 4; ++j) acc[i][j] = (f32x4){0.f, 0.f, 0.f, 0.f};

    for (int k0 = 0; k0 < K; k0 += BK) {
        __syncthreads();
#pragma unroll
        for (int s = 0; s < 2; ++s) {
            int c = tid + s * 256;
            int r = c >> 2, col = (c & 3) * 8;
            *(uint4*)&As[r * BK + col] = *(const uint4*)&A[(size_t)(bm + r) * K + k0 + col];
            *(uint4*)&Bs[r * BK + col] = *(const uint4*)&B[(size_t)(bn + r) * K + k0 + col];
        }
        __syncthreads();
        bf16x8 af[4], bfr[4];
#pragma unroll
        for (int i = 0; i < 4; ++i) {
            af[i]  = *(const bf16x8*)&As[(wm + i * 16 + row16) * BK + quad * 8];
            bfr[i] = *(const bf16x8*)&Bs[(wn + i * 16 + row16) * BK + quad * 8];
        }
#pragma unroll
        for (int i = 0; i < 4; ++i)
#pragma unroll
            for (int j = 0; j < 4; ++j)
                acc[i][j] = __builtin_amdgcn_mfma_f32_16x16x32_bf16(af[i], bfr[j], acc[i][j], 0, 0, 0);
    }

#pragma unroll
    for (int j = 0; j < 4; ++j) {
        int col = bn + wn + j * 16 + row16;
        float bsum = (bias1 ? bias1[col] : 0.f) + (bias2 ? bias2[col] : 0.f);
#pragma unroll
        for (int i = 0; i < 4; ++i) {
#pragma unroll
            for (int r = 0; r < 4; ++r) {
                int row = bm + wm + i * 16 + quad * 4 + r;
                float v = acc[i][j][r] + bsum;
                if (Cf) Cf[(size_t)row * N + col] = v;
                else    Cb[(size_t)row * N + col] = f2bf(v);
            }
        }
    }
}

// ---------------- persistent LSTM recurrence (register-direct MFMA) ----------------
// 256 blocks x 1024 threads, 1 block/CU (88KB LDS dummy forces it). Block b owns
// h[b*8..b*8+8) and gate rows {q*2048 + b*8 + j}. Wave w owns k-cols
// [w*128, w*128+128): 8 A-frags (both row groups) in 32 VGPRs.
// h exchange: 8-way REPLICATED mailbox of tagged 8B words (tag32 | 2xbf16).
// Producers write all 8 replicas (32 lanes, 1 store each); consumer block b polls
// only replica b&7 -> ~32 CUs per replica instead of 256 hammering one line set
// (r5's single mailbox line-serialized the LLC at ~2048 accesses/line/round).
// One barrier/step (LDSp double-buffered), single-wave epilogue, no fences.
#define LSTM_LDS 90112
__global__ __launch_bounds__(1024, 1) void k_lstm(
    const unsigned short* __restrict__ Whhb, // [8192,2048] bf16
    const unsigned short* __restrict__ xg,   // [4096,8192] bf16
    const float* __restrict__ h0, const float* __restrict__ c0,
    unsigned short* __restrict__ hsb,        // [4096,2048] bf16
    float* __restrict__ outHC,               // d_out + SEQ*NL : [hL(2048), cL(2048)]
    unsigned long long* __restrict__ hcomm)  // [2][8 replicas][1024] tagged words
{
    extern __shared__ char smem[];
    float* LDSp = (float*)smem;              // 2 buffers x [32 rows][stride 20]

    const int b = blockIdx.x, tid = threadIdx.x;
    const int wave = tid >> 6, lane = tid & 63;
    const int sub = lane & 15, quad = lane >> 4;

    // A-fragments: rows m=sub of row-group rg (rg0: gates q=0,1 ; rg1: q=2,3),
    // k-cols wave*128 + c*32 + quad*8.
    const int qa = (sub >> 3), qb = 2 + (sub >> 3), j = sub & 7;
    const unsigned short* wa = Whhb + ((size_t)(qa * HID + b * 8 + j)) * HID + wave * 128 + quad * 8;
    const unsigned short* wb = Whhb + ((size_t)(qb * HID + b * 8 + j)) * HID + wave * 128 + quad * 8;
    bf16x8 afrA[4], afrB[4];
#pragma unroll
    for (int c = 0; c < 4; ++c) {
        afrA[c] = *(const bf16x8*)(wa + c * 32);
        afrB[c] = *(const bf16x8*)(wb + c * 32);
    }

    float creg = 0.f;
    if (tid < 8) creg = c0[b * 8 + tid];

    for (int t = 0; t < SEQ; ++t) {
        // wave0 activation lanes prefetch their 4 x-gate values
        float xq0 = 0.f, xq1 = 0.f, xq2 = 0.f, xq3 = 0.f;
        if (wave == 0 && lane < 8) {
            const unsigned short* xr = xg + (size_t)t * G4 + b * 8 + lane;
            xq0 = bf2f(xr[0]);
            xq1 = bf2f(xr[2048]);
            xq2 = bf2f(xr[4096]);
            xq3 = bf2f(xr[6144]);
        }

        f32x4 acc0 = (f32x4){0.f, 0.f, 0.f, 0.f};
        f32x4 acc1 = (f32x4){0.f, 0.f, 0.f, 0.f};

        if (t == 0) {
#pragma unroll
            for (int c = 0; c < 4; ++c) {
                const float* hp = h0 + wave * 128 + c * 32 + quad * 8;
                float4 va = *(const float4*)hp;
                float4 vb = *(const float4*)(hp + 4);
                uint4 d;
                d.x = (unsigned)f2bf(va.x) | ((unsigned)f2bf(va.y) << 16);
                d.y = (unsigned)f2bf(va.z) | ((unsigned)f2bf(va.w) << 16);
                d.z = (unsigned)f2bf(vb.x) | ((unsigned)f2bf(vb.y) << 16);
                d.w = (unsigned)f2bf(vb.z) | ((unsigned)f2bf(vb.w) << 16);
                bf16x8 hf = __builtin_bit_cast(bf16x8, d);
                acc0 = __builtin_amdgcn_mfma_f32_16x16x32_bf16(afrA[c], hf, acc0, 0, 0, 0);
                acc1 = __builtin_amdgcn_mfma_f32_16x16x32_bf16(afrB[c], hf, acc1, 0, 0, 0);
            }
        } else {
            // lane L polls its own word in THIS block's replica (b&7)
            const unsigned long long* src =
                hcomm + (size_t)((t - 1) & 1) * 8192 + (size_t)(b & 7) * 1024 + wave * 64;
            const unsigned tag = (unsigned)t;
            unsigned long long x;
            for (;;) {
                x = aload(&src[lane]);
                if ((unsigned)(x >> 32) == tag) break;
                __builtin_amdgcn_s_sleep(1);
            }
            int myd = (int)(unsigned)x;
#pragma unroll
            for (int c = 0; c < 4; ++c) {
                const int sl = c * 16 + quad * 4;
                uint4 d;
                d.x = (unsigned)__shfl(myd, sl + 0);
                d.y = (unsigned)__shfl(myd, sl + 1);
                d.z = (unsigned)__shfl(myd, sl + 2);
                d.w = (unsigned)__shfl(myd, sl + 3);
                bf16x8 hf = __builtin_bit_cast(bf16x8, d);
                acc0 = __builtin_amdgcn_mfma_f32_16x16x32_bf16(afrA[c], hf, acc0, 0, 0, 0);
                acc1 = __builtin_amdgcn_mfma_f32_16x16x32_bf16(afrB[c], hf, acc1, 0, 0, 0);
            }
        }

        // partials -> double-buffered LDS, ONE barrier per step.
        float* P = LDSp + (t & 1) * 640;
        if (sub == 0) {
#pragma unroll
            for (int r = 0; r < 4; ++r) {
                P[(quad * 4 + r) * 20 + wave]      = acc0[r];
                P[(16 + quad * 4 + r) * 20 + wave] = acc1[r];
            }
        }
        __syncthreads();

        if (wave == 0) {
            float g = 0.f;
            if (lane < 32) {
                const float* rp = P + lane * 20;
                f32x4 s = *(const f32x4*)rp;
                s += *(const f32x4*)(rp + 4);
                s += *(const f32x4*)(rp + 8);
                s += *(const f32x4*)(rp + 12);
                g = s[0] + s[1] + s[2] + s[3];
            }
            // lane L (<32) holds gate row q=L>>3, j=L&7
            float gF = __shfl(g, 8 + lane);
            float gG = __shfl(g, 16 + lane);
            float gO = __shfl(g, 24 + lane);
            unsigned hv = 0;
            float cn = 0.f, hn = 0.f;
            if (lane < 8) {
                float gi = g  + xq0;
                float gf = gF + xq1;
                float gg = gG + xq2;
                float go = gO + xq3;
                float i_ = fsigm(gi);
                float f_ = fsigm(gf);
                float g_ = ftanh(gg);
                float o_ = fsigm(go);
                cn = f_ * creg + i_ * g_;
                hn = o_ * ftanh(cn);
                creg = cn;
                hv = (unsigned)f2bf(hn);
            }
            // publish word j=L&3 (pair h[2j],h[2j+1]) to replica L>>2 — 8 replicas
            {
                int jj = lane & 3;
                unsigned lo = (unsigned)__shfl((int)hv, 2 * jj);
                unsigned hi = (unsigned)__shfl((int)hv, 2 * jj + 1);
                if (lane < 32) {
                    unsigned long long wrd =
                        (((unsigned long long)(unsigned)(t + 1)) << 32)
                        | (unsigned long long)(lo | (hi << 16));
                    __hip_atomic_store(
                        &hcomm[(size_t)(t & 1) * 8192 + (size_t)(lane >> 2) * 1024 + b * 4 + jj],
                        wrd, __ATOMIC_RELAXED, __HIP_MEMORY_SCOPE_AGENT);
                }
            }
            if (lane < 8) {
                hsb[(size_t)t * HID + b * 8 + lane] = (unsigned short)hv;
                if (t == SEQ - 1) {
                    outHC[b * 8 + lane] = hn;
                    outHC[HID + b * 8 + lane] = cn;
                }
            }
        }
    }
}

// ---------------- relu + log_softmax over rows of 256 ----------------
__global__ __launch_bounds__(256) void k_softmax(const float* __restrict__ logits,
                                                 float* __restrict__ out) {
    int row = blockIdx.x * 4 + (threadIdx.x >> 6);
    int lane = threadIdx.x & 63;
    const float* Lr = logits + (size_t)row * NL;
    float4 v = *(const float4*)&Lr[lane * 4];
    v.x = fmaxf(v.x, 0.f); v.y = fmaxf(v.y, 0.f);
    v.z = fmaxf(v.z, 0.f); v.w = fmaxf(v.w, 0.f);
    float m = fmaxf(fmaxf(v.x, v.y), fmaxf(v.z, v.w));
#pragma unroll
    for (int off = 32; off > 0; off >>= 1) m = fmaxf(m, __shfl_xor(m, off));
    float e = __expf(v.x - m) + __expf(v.y - m) + __expf(v.z - m) + __expf(v.w - m);
#pragma unroll
    for (int off = 32; off > 0; off >>= 1) e += __shfl_xor(e, off);
    float ls = __logf(e) + m;
    float4 o;
    o.x = v.x - ls; o.y = v.y - ls; o.z = v.z - ls; o.w = v.w - ls;
    *(float4*)&out[(size_t)row * NL + lane * 4] = o;
}

extern "C" void kernel_launch(void* const* d_in, const int* in_sizes, int n_in,
                              void* d_out, int out_size, void* d_ws, size_t ws_size,
                              hipStream_t stream) {
    const int*   ids   = (const int*)d_in[0];
    const float* h0    = (const float*)d_in[1];
    const float* c0    = (const float*)d_in[2];
    const float* W_emb = (const float*)d_in[3];
    const float* W_ih  = (const float*)d_in[4];
    const float* W_hh  = (const float*)d_in[5];
    const float* b_ih  = (const float*)d_in[6];
    const float* b_hh  = (const float*)d_in[7];
    const float* W_out = (const float*)d_in[8];
    const float* b_out = (const float*)d_in[9];
    float* out = (float*)d_out;

    char* ws = (char*)d_ws;
    unsigned short* xg    = (unsigned short*)(ws);                 // 64MB  [4096,8192] bf16
    unsigned short* hsb   = (unsigned short*)(ws + 67108864);      // 16MB  [4096,2048] bf16
    unsigned short* Wihb  = (unsigned short*)(ws + 83886080);      // 16MB
    unsigned short* embb  = (unsigned short*)(ws + 100663296);     // 8MB
    unsigned short* Woutb = (unsigned short*)(ws + 109051904);     // 1MB
    float*          logit = (float*)(ws + 110100480);              // 4MB
    unsigned short* Whhb  = (unsigned short*)(ws + 114294784);     // 32MB [8192,2048] bf16
    unsigned long long* hcomm = (unsigned long long*)(ws + 147849216); // 128KB (0xAA poison != any tag)

    k_f2b<<<(G4 * EMB / 4 + 255) / 256, 256, 0, stream>>>(W_ih, Wihb, G4 * EMB);
    k_f2b<<<(NL * HID / 4 + 255) / 256, 256, 0, stream>>>(W_out, Woutb, NL * HID);
    k_f2b<<<(G4 * HID / 4 + 255) / 256, 256, 0, stream>>>(W_hh, Whhb, G4 * HID);
    k_emb<<<SEQ, 256, 0, stream>>>(ids, W_emb, embb);

    dim3 g1(SEQ / BM, G4 / BN);
    k_gemm_bt<<<g1, 256, 0, stream>>>(embb, Wihb, b_ih, b_hh, nullptr, xg, SEQ, G4, EMB);

    hipFuncSetAttribute((const void*)k_lstm, hipFuncAttributeMaxDynamicSharedMemorySize, LSTM_LDS);
    k_lstm<<<256, 1024, LSTM_LDS, stream>>>(Whhb, xg, h0, c0, hsb, out + (size_t)SEQ * NL, hcomm);

    dim3 g2(SEQ / BM, NL / BN);
    k_gemm_bt<<<g2, 256, 0, stream>>>(hsb, Woutb, b_out, nullptr, logit, nullptr, SEQ, NL, HID);

    k_softmax<<<SEQ / 4, 256, 0, stream>>>(logit, out);
}